// Round 6
// baseline (406.503 us; speedup 1.0000x reference)
//
#include <hip/hip_runtime.h>
#include <hip/hip_fp16.h>

#define DIMQ 65536
#define BQ 128

// ---------------------------------------------------------------------------
// CNOT ring as GF(2)-linear index permutation y = M x (verified R1-R5, absmax 0)
// ---------------------------------------------------------------------------
__host__ __device__ constexpr unsigned ring_map(unsigned x) {
  for (int bc = 15; bc >= 1; --bc) x ^= ((x >> bc) & 1u) << (bc - 1);
  x ^= (x & 1u) << 15;
  return x;
}
__host__ __device__ constexpr unsigned ring_unmap(unsigned y) {
  y ^= (y & 1u) << 15;
  for (int bc = 1; bc <= 15; ++bc) y ^= ((y >> bc) & 1u) << (bc - 1);
  return y;
}
__host__ __device__ constexpr unsigned row_of(int b) {
  return (b <= 14) ? ((0xFFFFu << b) & 0xFFFFu) : 0x7FFFu;
}
__host__ __device__ constexpr int popc16(unsigned v) {
  int c = 0; for (int i = 0; i < 16; ++i) c += (v >> i) & 1; return c;
}
static_assert(ring_unmap(ring_map(0x1234u)) == 0x1234u, "inv");
static_assert(ring_map(ring_unmap(0x5A5Au)) == 0x5A5Au, "inv");
__host__ __device__ constexpr bool check_rows() {
  const unsigned xs[4] = {0x1234u, 0x8001u, 0xFFFFu, 0x0F0Fu};
  for (int b = 0; b < 16; ++b)
    for (int i = 0; i < 4; ++i)
      if (((ring_map(xs[i]) >> b) & 1u) != (unsigned)(popc16(xs[i] & row_of(b)) & 1))
        return false;
  return true;
}
static_assert(check_rows(), "row_of = row b of M");

// P2 phase-B direction pinning: lanes = e2..e7, regs r0->e0,r1->e1,r2->e13,r3->e14,r4->e15
static_assert(ring_unmap(1u << 0) == 0xC001u, "u0  = e0^e14^e15 -> reg mask 25");
static_assert(ring_unmap(1u << 1) == 0x0003u, "u1  = e0^e1      -> reg mask 3");
static_assert(ring_unmap(1u << 2) == 0x0006u, "u2  = e1^e2      -> mixed reg2/lane1");
static_assert(ring_unmap(1u << 3) == (3u  << 2), "u3 -> lane mask 3");
static_assert(ring_unmap(1u << 4) == (6u  << 2), "u4 -> lane mask 6");
static_assert(ring_unmap(1u << 5) == (12u << 2), "u5 -> lane mask 12");
static_assert(ring_unmap(1u << 6) == (24u << 2), "u6 -> lane mask 24");
static_assert(ring_unmap(1u << 7) == (48u << 2), "u7 -> lane mask 48");
// P2 phase-A direction pinning (regs e11..e15)
static_assert(ring_unmap(1u << 12) == (3u  << 11), "u12 -> reg mask 3");
static_assert(ring_unmap(1u << 13) == (6u  << 11), "u13 -> reg mask 6");
static_assert(ring_unmap(1u << 14) == (12u << 11), "u14 -> reg mask 12");
static_assert(ring_unmap(1u << 15) == (24u << 11), "u15 -> reg mask 24");
// P4 chain + P3 relabel identities (verified R4/R5)
static_assert(ring_map(0x0C00u) == 0x0800u, "M(e10^e11)=e11");
static_assert(ring_map(0xC000u) == 0x8000u, "M(e14^e15)=e15");

// 13-bit local coords of the P3 block tile in z-space: z0..z11 + z15
__host__ __device__ constexpr unsigned loc13(unsigned z16) {
  return (z16 & 0x0FFFu) | (((z16 >> 15) & 1u) << 12);
}
__host__ __device__ constexpr unsigned sw13(unsigned i) { return i ^ ((i >> 5) & 31u); }
// P2 fp16-LDS swizzle: both phases <=2-way banked (verified by kernel analysis)
__host__ __device__ constexpr unsigned swzh(unsigned loc) {
  return loc ^ ((loc >> 5) & 31u);
}

struct Tab32u { unsigned v[32]; };
__host__ __device__ constexpr Tab32u make_rx2() {
  Tab32u t{}; for (int r = 0; r < 32; ++r) t.v[r] = (unsigned)r << 11; return t;
}
__host__ __device__ constexpr Tab32u make_rxb() {   // P2 phase-B reg dims
  Tab32u t{};
  for (int r = 0; r < 32; ++r)
    t.v[r] = (unsigned)(r & 1) | (((unsigned)(r >> 1) & 1) << 1) |
             (((unsigned)(r >> 2) & 1) << 13) | (((unsigned)(r >> 3) & 1) << 14) |
             (((unsigned)(r >> 4) & 1) << 15);
  return t;
}
static_assert(make_rxb().v[25] == 0xC001u, "RXB linear: mask25 = u0");
static_assert(make_rxb().v[3]  == 0x0003u, "RXB mask3 = u1");
__host__ __device__ constexpr Tab32u make_swrl() {  // P3 relabel-write slot offsets
  Tab32u t{}; for (int r = 0; r < 32; ++r) t.v[r] = sw13(loc13(ring_map((unsigned)r)));
  return t;
}
__host__ __device__ constexpr Tab32u make_sw2() {
  Tab32u t{}; for (int r = 0; r < 32; ++r) t.v[r] = sw13((unsigned)r << 6);
  return t;
}
__host__ __device__ constexpr Tab32u make_rp3() {
  Tab32u t{}; for (int r = 0; r < 32; ++r) t.v[r] = (unsigned)r << 6; return t;
}
__host__ __device__ constexpr Tab32u make_t4() {    // P4 reg-chain offsets (bits 10..15)
  Tab32u t{};
  for (int r = 0; r < 32; ++r) {
    unsigned r0 = r & 1, r1 = (r >> 1) & 1, r2 = (r >> 2) & 1, r3 = (r >> 3) & 1, r4 = (r >> 4) & 1;
    t.v[r] = (r0 << 10) | ((r0 ^ r1) << 11) | ((r1 ^ r2) << 12) |
             ((r2 ^ r3) << 13) | ((r3 ^ r4) << 14) | (r4 << 15);
  }
  return t;
}
__device__ constexpr Tab32u RX2  = make_rx2();
__device__ constexpr Tab32u RXB  = make_rxb();
__device__ constexpr Tab32u SWRL = make_swrl();
__device__ constexpr Tab32u SW2  = make_sw2();
__device__ constexpr Tab32u RP3  = make_rp3();
__device__ constexpr Tab32u T4   = make_t4();

// ---------------------------------------------------------------------------
// Gate coefficients U = RZ(phi) @ RY(theta), wave-uniform.
// ---------------------------------------------------------------------------
struct U2 { float r00, i00, r01, i01, r10, i10, r11, i11; };

__global__ void k_prep(const float* __restrict__ params, float* __restrict__ uc) {
  int g = threadIdx.x;
  if (g >= 48) return;
  float th = 0.5f * params[g * 2 + 0];
  float ph = 0.5f * params[g * 2 + 1];
  float st, ct, sp, cp;
  __sincosf(th, &st, &ct);
  __sincosf(ph, &sp, &cp);
  float* u = uc + g * 8;
  u[0] =  cp * ct; u[1] = -sp * ct;
  u[2] = -cp * st; u[3] =  sp * st;
  u[4] =  cp * st; u[5] =  sp * st;
  u[6] =  cp * ct; u[7] =  sp * ct;
}

__device__ inline U2 load_u(const float* __restrict__ uc, int d, int w) {
  const float* u = uc + (d * 16 + w) * 8;
  U2 r;
  r.r00 = u[0]; r.i00 = u[1]; r.r01 = u[2]; r.i01 = u[3];
  r.r10 = u[4]; r.i10 = u[5]; r.r11 = u[6]; r.i11 = u[7];
  return r;
}

__device__ inline float2 cmadd2(float cr, float ci, float2 a, float dr, float di, float2 b) {
  float x = fmaf(cr, a.x, fmaf(-ci, a.y, fmaf(dr, b.x, -di * b.y)));
  float y = fmaf(cr, a.y, fmaf( ci, a.x, fmaf(dr, b.y,  di * b.x)));
  return make_float2(x, y);
}

__device__ inline float2 h_to_f2(float bits) {
  __half2 h = __builtin_bit_cast(__half2, bits);
  return __half22float2(h);
}
__device__ inline float f2_to_h(float2 v) {
  __half2 h = __float22half2_rn(v);
  return __builtin_bit_cast(float, h);
}

template <int MASK>
__device__ inline float lane_xor_f(float v) {
  if constexpr (MASK == 1) {
    return __int_as_float(__builtin_amdgcn_update_dpp(
        0, __float_as_int(v), 0xB1, 0xF, 0xF, true));
  } else if constexpr (MASK == 2) {
    return __int_as_float(__builtin_amdgcn_update_dpp(
        0, __float_as_int(v), 0x4E, 0xF, 0xF, true));
  } else if constexpr (MASK == 3) {
    return __int_as_float(__builtin_amdgcn_update_dpp(
        0, __float_as_int(v), 0x1B, 0xF, 0xF, true));
  } else if constexpr (MASK < 32) {
    return __int_as_float(__builtin_amdgcn_ds_swizzle(
        __float_as_int(v), (MASK << 10) | 0x1F));
  } else {
    return __shfl_xor(v, MASK, 64);
  }
}

// ---------------- natural gates (verified R1-R5) ----------------
template <int K>
__device__ inline void reg_gate(float2 (&a)[32], const U2 u) {
#pragma unroll
  for (int l = 0; l < 32; ++l) {
    if (l & (1 << K)) continue;
    const int p = l | (1 << K);
    const float2 A = a[l], B = a[p];
    a[l] = cmadd2(u.r00, u.i00, A, u.r01, u.i01, B);
    a[p] = cmadd2(u.r10, u.i10, A, u.r11, u.i11, B);
  }
}

template <int MASK>
__device__ inline void lane_gate(float2 (&a)[32], const U2 u, int lane) {
  const bool hi = (lane & MASK) != 0;
  const float c0r = hi ? u.r11 : u.r00, c0i = hi ? u.i11 : u.i00;
  const float c1r = hi ? u.r10 : u.r01, c1i = hi ? u.i10 : u.i01;
#pragma unroll
  for (int l = 0; l < 32; ++l) {
    float2 px = make_float2(lane_xor_f<MASK>(a[l].x), lane_xor_f<MASK>(a[l].y));
    a[l] = cmadd2(c0r, c0i, a[l], c1r, c1i, px);
  }
}

template <int MASK>
__device__ inline void lane_gate_s(float2 (&a)[32], const U2 u, int hi) {
  const float c0r = hi ? u.r11 : u.r00, c0i = hi ? u.i11 : u.i00;
  const float c1r = hi ? u.r10 : u.r01, c1i = hi ? u.i10 : u.i01;
#pragma unroll
  for (int l = 0; l < 32; ++l) {
    float2 px = make_float2(lane_xor_f<MASK>(a[l].x), lane_xor_f<MASK>(a[l].y));
    a[l] = cmadd2(c0r, c0i, a[l], c1r, c1i, px);
  }
}

// ---------------- fused (conjugated) gates (verified R3-R5) ----------------
template <int PM>
__device__ inline void fused_reg_gate(float2 (&a)[32], const U2 u, unsigned xK,
                                      const unsigned (&RX)[32], unsigned row) {
  constexpr int LB = PM & (-PM);
#pragma unroll
  for (int l = 0; l < 32; ++l) {
    if (l & LB) continue;
    const int p = l ^ PM;
    const int s = __popc((xK ^ RX[l]) & row) & 1;
    const float2 A = a[l], B = a[p];
    const float c0r = s ? u.r11 : u.r00, c0i = s ? u.i11 : u.i00;
    const float c1r = s ? u.r10 : u.r01, c1i = s ? u.i10 : u.i01;
    const float d0r = s ? u.r00 : u.r11, d0i = s ? u.i00 : u.i11;
    const float d1r = s ? u.r01 : u.r10, d1i = s ? u.i01 : u.i10;
    a[l] = cmadd2(c0r, c0i, A, c1r, c1i, B);
    a[p] = cmadd2(d1r, d1i, A, d0r, d0i, B);
  }
}

template <int LM>
__device__ inline void fused_lane_gate(float2 (&a)[32], const U2 u, unsigned xK,
                                       const unsigned (&RX)[32], unsigned row) {
#pragma unroll
  for (int l = 0; l < 32; ++l) {
    float2 px = make_float2(lane_xor_f<LM>(a[l].x), lane_xor_f<LM>(a[l].y));
    const int s = __popc((xK ^ RX[l]) & row) & 1;
    const float c0r = s ? u.r11 : u.r00, c0i = s ? u.i11 : u.i00;
    const float c1r = s ? u.r10 : u.r01, c1i = s ? u.i10 : u.i01;
    a[l] = cmadd2(c0r, c0i, a[l], c1r, c1i, px);
  }
}

template <int LM, int PM>
__device__ inline void fused_mixed_gate(float2 (&a)[32], const U2 u, unsigned xK,
                                        const unsigned (&RX)[32], unsigned row) {
  constexpr int LB = PM & (-PM);
#pragma unroll
  for (int l = 0; l < 32; ++l) {
    if (l & LB) continue;
    const int p = l ^ PM;
    const float2 A = a[l], B = a[p];
    float2 pa = make_float2(lane_xor_f<LM>(B.x), lane_xor_f<LM>(B.y));
    float2 pb = make_float2(lane_xor_f<LM>(A.x), lane_xor_f<LM>(A.y));
    const int sl = __popc((xK ^ RX[l]) & row) & 1;
    const int sp = __popc((xK ^ RX[p]) & row) & 1;
    {
      const float c0r = sl ? u.r11 : u.r00, c0i = sl ? u.i11 : u.i00;
      const float c1r = sl ? u.r10 : u.r01, c1i = sl ? u.i10 : u.i01;
      a[l] = cmadd2(c0r, c0i, A, c1r, c1i, pa);
    }
    {
      const float c0r = sp ? u.r11 : u.r00, c0i = sp ? u.i11 : u.i00;
      const float c1r = sp ? u.r10 : u.r01, c1i = sp ? u.i10 : u.i01;
      a[p] = cmadd2(c0r, c0i, B, c1r, c1i, pb);
    }
  }
}

// ---------------------------------------------------------------------------
// P1: L0 on x0..x10 (wires 15..5). fp32 float4 in, fp16 out packed 16B/lane.
// ---------------------------------------------------------------------------
__global__ __launch_bounds__(256, 4)
void k_p1(const float* __restrict__ in, __half2* __restrict__ dstb,
          const float* __restrict__ uc) {
  const int b = blockIdx.x >> 3;
  const unsigned hi = blockIdx.x & 7;
  const unsigned wg = threadIdx.x >> 6;
  const unsigned lane = threadIdx.x & 63;
  const unsigned xK = (hi << 13) | (wg << 11) | (lane << 2);
  const float* src = in + (size_t)b * DIMQ;
  float2 a[32];
#pragma unroll
  for (int c = 0; c < 8; ++c) {
    float4 q = *(const float4*)(src + xK + ((unsigned)c << 8));
    a[c * 4 + 0] = make_float2(q.x, 0.f);
    a[c * 4 + 1] = make_float2(q.y, 0.f);
    a[c * 4 + 2] = make_float2(q.z, 0.f);
    a[c * 4 + 3] = make_float2(q.w, 0.f);
  }
  reg_gate<0>(a, load_u(uc, 0, 15));
  reg_gate<1>(a, load_u(uc, 0, 14));
  lane_gate<1 >(a, load_u(uc, 0, 13), lane);
  lane_gate<2 >(a, load_u(uc, 0, 12), lane);
  lane_gate<4 >(a, load_u(uc, 0, 11), lane);
  lane_gate<8 >(a, load_u(uc, 0, 10), lane);
  lane_gate<16>(a, load_u(uc, 0, 9 ), lane);
  lane_gate<32>(a, load_u(uc, 0, 8 ), lane);
  reg_gate<2>(a, load_u(uc, 0, 7));
  reg_gate<3>(a, load_u(uc, 0, 6));
  reg_gate<4>(a, load_u(uc, 0, 5));
  float* dst = (float*)(dstb + (size_t)b * DIMQ);   // half2 units (4 B/amp)
#pragma unroll
  for (int c = 0; c < 8; ++c) {
    float4 q;
    q.x = f2_to_h(a[c * 4 + 0]);
    q.y = f2_to_h(a[c * 4 + 1]);
    q.z = f2_to_h(a[c * 4 + 2]);
    q.w = f2_to_h(a[c * 4 + 3]);
    *(float4*)(dst + xK + ((unsigned)c << 8)) = q;   // 16B/lane contiguous
  }
}

// ---------------------------------------------------------------------------
// P2 (2-phase, fp16 LDS 32KB, 4 blocks/CU): tile span{e0..e7, e11..e15}.
//  pA: regs e11..e15, lanes e0..e5, waves e6,e7: L0 wires 4..0 + fused L1
//      u12..u15 (verified calls). fp16 in.
//  fp16 LDS handoff (swzh: both phases <=2-way banked).
//  pB: regs {e0,e1,e13,e14,e15}, lanes e2..e7, waves e11,e12: fused L1 u0..u7;
//      fp16 store as float4 (16B/lane).
// ---------------------------------------------------------------------------
__global__ __launch_bounds__(256, 4)
void k_p2(const __half2* __restrict__ srcb, __half2* __restrict__ dstb,
          const float* __restrict__ uc) {
  __shared__ float ldsh[8192];   // 32 KB, 1 amp per float slot
  const int b = blockIdx.x >> 3;
  const unsigned t8 = blockIdx.x & 7;
  const unsigned wv = threadIdx.x >> 6;
  const unsigned lane = threadIdx.x & 63;
  const float* src = (const float*)(srcb + (size_t)b * DIMQ);
  // ---- phase A ----
  const unsigned xKa = lane | (wv << 6) | (t8 << 8);
  float2 a[32];
#pragma unroll
  for (int r = 0; r < 32; ++r)
    a[r] = h_to_f2(src[((unsigned)r << 11) | xKa]);
  reg_gate<0>(a, load_u(uc, 0, 4));
  reg_gate<1>(a, load_u(uc, 0, 3));
  reg_gate<2>(a, load_u(uc, 0, 2));
  reg_gate<3>(a, load_u(uc, 0, 1));
  reg_gate<4>(a, load_u(uc, 0, 0));
  fused_reg_gate<3 >(a, load_u(uc, 1, 3), xKa, RX2.v, row_of(12));
  fused_reg_gate<6 >(a, load_u(uc, 1, 2), xKa, RX2.v, row_of(13));
  fused_reg_gate<12>(a, load_u(uc, 1, 1), xKa, RX2.v, row_of(14));
  fused_reg_gate<24>(a, load_u(uc, 1, 0), xKa, RX2.v, row_of(15));
  // LDS handoff (loc13 bits: e0..e7 -> 0..7, e11..e15 -> 8..12)
#pragma unroll
  for (int r = 0; r < 32; ++r)
    ldsh[swzh(lane | (wv << 6) | ((unsigned)r << 8))] = f2_to_h(a[r]);
  __syncthreads();
  // ---- phase B ----
#pragma unroll
  for (int r = 0; r < 32; ++r)
    a[r] = h_to_f2(ldsh[swzh(((unsigned)r & 3u) | (lane << 2) | (wv << 8) |
                             (((unsigned)r >> 2) << 10))]);
  const unsigned xKb = (lane << 2) | (t8 << 8) | (wv << 11);
  fused_reg_gate<25>(a, load_u(uc, 1, 15), xKb, RXB.v, 0xFFFFu);       // b=0
  fused_reg_gate<3 >(a, load_u(uc, 1, 14), xKb, RXB.v, row_of(1));     // b=1
  fused_mixed_gate<1, 2>(a, load_u(uc, 1, 13), xKb, RXB.v, row_of(2)); // b=2
  fused_lane_gate<3 >(a, load_u(uc, 1, 12), xKb, RXB.v, row_of(3));
  fused_lane_gate<6 >(a, load_u(uc, 1, 11), xKb, RXB.v, row_of(4));
  fused_lane_gate<12>(a, load_u(uc, 1, 10), xKb, RXB.v, row_of(5));
  fused_lane_gate<24>(a, load_u(uc, 1, 9 ), xKb, RXB.v, row_of(6));
  fused_lane_gate<48>(a, load_u(uc, 1, 8 ), xKb, RXB.v, row_of(7));
  float* dst = (float*)(dstb + (size_t)b * DIMQ);
#pragma unroll
  for (int g = 0; g < 8; ++g) {
    float4 q;
    q.x = f2_to_h(a[g * 4 + 0]);
    q.y = f2_to_h(a[g * 4 + 1]);
    q.z = f2_to_h(a[g * 4 + 2]);
    q.w = f2_to_h(a[g * 4 + 3]);
    *(float4*)(dst + ((lane << 2) | (t8 << 8) | (wv << 11) | ((unsigned)g << 13))) = q;
  }
}

// ---------------------------------------------------------------------------
// P3: LDS-routed ring relabel (verified R4/R5), 4 waves/SIMD.
// ---------------------------------------------------------------------------
__global__ __launch_bounds__(256, 4)
void k_p3(const __half2* __restrict__ srcb, __half2* __restrict__ dstb,
          const float* __restrict__ uc) {
  __shared__ float lds[8192];
  const int b = blockIdx.x >> 3;
  const unsigned tb = blockIdx.x & 7;
  const unsigned x12 = tb & 1u, x13 = (tb >> 1) & 1u, tt = tb >> 2;
  const unsigned tid = threadIdx.x;
  const float* src = (const float*)(srcb + (size_t)b * DIMQ);
  float* dst = (float*)(dstb + (size_t)b * DIMQ);
#pragma unroll
  for (unsigned c = 0; c < 2; ++c) {
    const unsigned gbase = (c << 14) | ((c ^ tt) << 15) | (x13 << 13) | (x12 << 12);
#pragma unroll
    for (unsigned j = 0; j < 4; ++j) {
      const unsigned e = j * 1024u + tid * 4u;
      float4 q = *(const float4*)(src + gbase + e);
      const unsigned idx = (c << 12) | e;
      const unsigned m = (idx >> 5) & 31u;
      if (m & 1u) { float s0 = q.x; q.x = q.y; q.y = s0; s0 = q.z; q.z = q.w; q.w = s0; }
      if (m & 2u) { float s0 = q.x, s1 = q.y; q.x = q.z; q.y = q.w; q.z = s0; q.w = s1; }
      *(float4*)&lds[(idx ^ m) & ~3u] = q;
    }
  }
  __syncthreads();
  const unsigned lane = tid & 63u, wv = tid >> 6;
  const unsigned w0 = wv & 1u, w1 = wv >> 1;
  const unsigned g = (lane ^ (lane >> 1)) & 63u;
  const unsigned x5 = (lane ^ w0) & 1u;
  const unsigned xloc  = (x5 << 5) | (g << 6) | (w1 << 12);
  const unsigned xfull = (x5 << 5) | (g << 6) | (x12 << 12) | (x13 << 13)
                       | (w1 << 14) | ((w1 ^ tt) << 15);
  const unsigned sb1 = sw13(xloc);
  float2 a[32];
#pragma unroll
  for (unsigned r = 0; r < 32; ++r) a[r] = h_to_f2(lds[sb1 ^ r]);
  lane_gate_s<4 >(a, load_u(uc, 1, 7), __popc(xfull & row_of(8 )) & 1);
  lane_gate_s<8 >(a, load_u(uc, 1, 6), __popc(xfull & row_of(9 )) & 1);
  lane_gate_s<16>(a, load_u(uc, 1, 5), __popc(xfull & row_of(10)) & 1);
  lane_gate_s<32>(a, load_u(uc, 1, 4), __popc(xfull & row_of(11)) & 1);
  const unsigned swzr = sw13(loc13(ring_map(xfull)));
  __syncthreads();
#pragma unroll
  for (unsigned r = 0; r < 32; ++r) lds[swzr ^ SWRL.v[r]] = f2_to_h(a[r]);
  __syncthreads();
  const unsigned z12 = x12 ^ x13 ^ tt, z13 = x13 ^ tt, z14 = tt;
  const unsigned zloc2 = lane | (w0 << 11) | (w1 << 12);
  const unsigned sb2 = sw13(zloc2);
  const unsigned z16b = lane | (w0 << 11) | (z12 << 12) | (z13 << 13)
                      | (z14 << 14) | (w1 << 15);
#pragma unroll
  for (unsigned r = 0; r < 32; ++r) a[r] = h_to_f2(lds[sb2 ^ SW2.v[r]]);
  fused_lane_gate<3 >(a, load_u(uc, 2, 14), z16b, RP3.v, row_of(1));
  fused_lane_gate<6 >(a, load_u(uc, 2, 13), z16b, RP3.v, row_of(2));
  fused_lane_gate<12>(a, load_u(uc, 2, 12), z16b, RP3.v, row_of(3));
  fused_lane_gate<24>(a, load_u(uc, 2, 11), z16b, RP3.v, row_of(4));
  fused_lane_gate<48>(a, load_u(uc, 2, 10), z16b, RP3.v, row_of(5));
  fused_mixed_gate<32, 1>(a, load_u(uc, 2, 9), z16b, RP3.v, row_of(6));
  fused_reg_gate<3 >(a, load_u(uc, 2, 8), z16b, RP3.v, row_of(7));
  fused_reg_gate<6 >(a, load_u(uc, 2, 7), z16b, RP3.v, row_of(8));
  fused_reg_gate<12>(a, load_u(uc, 2, 6), z16b, RP3.v, row_of(9));
  fused_reg_gate<24>(a, load_u(uc, 2, 5), z16b, RP3.v, row_of(10));
#pragma unroll
  for (unsigned r = 0; r < 32; ++r)
    dst[z16b ^ (r << 6)] = f2_to_h(a[r]);
}

// ---------------------------------------------------------------------------
// P4: unchanged (verified R4/R5). L2 wires 4..0 + wire 15, fused epilogue.
// ---------------------------------------------------------------------------
__global__ __launch_bounds__(256, 4)
void k_p4(const __half2* __restrict__ srcb, float* __restrict__ partials,
          const float* __restrict__ uc) {
  const int b = blockIdx.x >> 3;
  const unsigned q = blockIdx.x & 7;
  const unsigned wg = threadIdx.x >> 6, lane = threadIdx.x & 63u;
  const unsigned zb = lane | ((wg & 1u) << 6) | ((wg >> 1) << 7) | ((q & 1u) << 8)
                    | (((q >> 1) & 1u) << 9) | ((q >> 2) << 10);
  const float* src = (const float*)(srcb + (size_t)b * DIMQ);
  float2 a[32];
#pragma unroll
  for (unsigned r = 0; r < 32; ++r) a[r] = h_to_f2(src[zb ^ T4.v[r]]);
  fused_reg_gate<1 >(a, load_u(uc, 2, 4), zb, T4.v, row_of(11));
  fused_reg_gate<2 >(a, load_u(uc, 2, 3), zb, T4.v, row_of(12));
  fused_reg_gate<4 >(a, load_u(uc, 2, 2), zb, T4.v, row_of(13));
  fused_reg_gate<8 >(a, load_u(uc, 2, 1), zb, T4.v, row_of(14));
  fused_reg_gate<16>(a, load_u(uc, 2, 0), zb, T4.v, row_of(15));
  fused_mixed_gate<1, 16>(a, load_u(uc, 2, 15), zb, T4.v, 0xFFFFu);
  const unsigned ybase = ring_map(zb);
  float acc[16];
#pragma unroll
  for (int w = 0; w < 16; ++w) acc[w] = 0.f;
#pragma unroll
  for (unsigned r = 0; r < 32; ++r) {
    const float p = fmaf(a[r].x, a[r].x, a[r].y * a[r].y);
    const unsigned y = ybase ^ (r << 11);
#pragma unroll
    for (int w = 0; w < 16; ++w)
      acc[w] += ((y >> (15 - w)) & 1u) ? -p : p;
  }
#pragma unroll
  for (int w = 0; w < 16; ++w) {
    float s = acc[w];
    s += __shfl_xor(s, 1, 64);
    s += __shfl_xor(s, 2, 64);
    s += __shfl_xor(s, 4, 64);
    s += __shfl_xor(s, 8, 64);
    s += __shfl_xor(s, 16, 64);
    s += __shfl_xor(s, 32, 64);
    acc[w] = s;
  }
  if (lane == 0) {
    const unsigned t = q * 4 + wg;
    float* dstp = partials + ((size_t)b * 32 + t) * 16;
#pragma unroll
    for (int w = 0; w < 16; ++w) dstp[w] = acc[w];
  }
}

__global__ __launch_bounds__(256)
void k_head(const float* __restrict__ partials, const float* __restrict__ hw,
            const float* __restrict__ hb, float* __restrict__ out) {
  const int b = blockIdx.x;
  const int t = threadIdx.x;
  const int w = t & 15;
  const int i = t >> 4;
  float s = partials[((size_t)b * 32 + i) * 16 + w] +
            partials[((size_t)b * 32 + i + 16) * 16 + w];
  __shared__ float red[256];
  __shared__ float feats[16];
  red[t] = s;
  __syncthreads();
  if (t < 16) {
    float f = 0.f;
    for (int j = 0; j < 16; ++j) f += red[j * 16 + t];
    feats[t] = f;
  }
  __syncthreads();
  if (t == 0) {
    float o = hb[0];
    for (int w2 = 0; w2 < 16; ++w2) o = fmaf(feats[w2], hw[w2], o);
    out[b] = o;
  }
}

extern "C" void kernel_launch(void* const* d_in, const int* in_sizes, int n_in,
                              void* d_out, int out_size, void* d_ws, size_t ws_size,
                              hipStream_t stream) {
  const float* state  = (const float*)d_in[0];   // (128, 65536) f32
  const float* params = (const float*)d_in[1];   // (3, 16, 2)   f32
  const float* head_w = (const float*)d_in[2];   // (1, 16)      f32
  const float* head_b = (const float*)d_in[3];   // (1,)         f32
  float* out = (float*)d_out;                    // (128,)       f32

  // ws: three 32 MB fp16 hop buffers + partials + uc
  __half2* bufA = (__half2*)d_ws;
  __half2* bufB = bufA + (size_t)DIMQ * BQ;
  __half2* bufC = bufB + (size_t)DIMQ * BQ;
  float*   partials = (float*)(bufC + (size_t)DIMQ * BQ);
  float*   uc = partials + (size_t)BQ * 32 * 16;

  k_prep<<<dim3(1), dim3(64), 0, stream>>>(params, uc);

  const dim3 g(1024), blk(256);
  k_p1<<<g, blk, 0, stream>>>(state, bufA, uc);
  k_p2<<<g, blk, 0, stream>>>(bufA, bufB, uc);
  k_p3<<<g, blk, 0, stream>>>(bufB, bufC, uc);
  k_p4<<<g, blk, 0, stream>>>(bufC, partials, uc);
  k_head<<<dim3(128), blk, 0, stream>>>(partials, head_w, head_b, out);
}

// Round 7
// 237.610 us; speedup vs baseline: 1.7108x; 1.7108x over previous
//
#include <hip/hip_runtime.h>
#include <hip/hip_fp16.h>

#define DIMQ 65536
#define BQ 128

typedef float v2f __attribute__((ext_vector_type(2)));

// ---------------------------------------------------------------------------
// CNOT ring as GF(2)-linear index permutation y = M x (verified R1-R6, absmax 0)
// ---------------------------------------------------------------------------
__host__ __device__ constexpr unsigned ring_map(unsigned x) {
  for (int bc = 15; bc >= 1; --bc) x ^= ((x >> bc) & 1u) << (bc - 1);
  x ^= (x & 1u) << 15;
  return x;
}
__host__ __device__ constexpr unsigned ring_unmap(unsigned y) {
  y ^= (y & 1u) << 15;
  for (int bc = 1; bc <= 15; ++bc) y ^= ((y >> bc) & 1u) << (bc - 1);
  return y;
}
__host__ __device__ constexpr unsigned row_of(int b) {
  return (b <= 14) ? ((0xFFFFu << b) & 0xFFFFu) : 0x7FFFu;
}
__host__ __device__ constexpr int popc16(unsigned v) {
  int c = 0; for (int i = 0; i < 16; ++i) c += (v >> i) & 1; return c;
}
static_assert(ring_unmap(ring_map(0x1234u)) == 0x1234u, "inv");
static_assert(ring_map(ring_unmap(0x5A5Au)) == 0x5A5Au, "inv");
__host__ __device__ constexpr bool check_rows() {
  const unsigned xs[4] = {0x1234u, 0x8001u, 0xFFFFu, 0x0F0Fu};
  for (int b = 0; b < 16; ++b)
    for (int i = 0; i < 4; ++i)
      if (((ring_map(xs[i]) >> b) & 1u) != (unsigned)(popc16(xs[i] & row_of(b)) & 1))
        return false;
  return true;
}
static_assert(check_rows(), "row_of = row b of M");
// directions used below (verified R4 structure)
static_assert(ring_unmap(1u << 0)  == 0xC001u, "u0 = e0^e14^e15");
static_assert(ring_unmap(1u << 6)  == 0x0060u, "u6 = e5^e6");
static_assert(ring_unmap(1u << 11) == 0x0C00u, "u11 = e10^e11");
static_assert(ring_unmap(1u << 15) == 0xC000u, "u15 = e14^e15");
static_assert(ring_map(0x0C00u) == 0x0800u, "M(e10^e11)=e11");
static_assert(ring_map(0xC000u) == 0x8000u, "M(e14^e15)=e15");

// 13-bit local coords of the P3 block tile in z-space: z0..z11 + z15
__host__ __device__ constexpr unsigned loc13(unsigned z16) {
  return (z16 & 0x0FFFu) | (((z16 >> 15) & 1u) << 12);
}
__host__ __device__ constexpr unsigned sw13(unsigned i) { return i ^ ((i >> 5) & 31u); }

struct Tab32u { unsigned v[32]; };
__host__ __device__ constexpr Tab32u make_rx2() {
  Tab32u t{}; for (int r = 0; r < 32; ++r) t.v[r] = (unsigned)r << 11; return t;
}
__host__ __device__ constexpr Tab32u make_swrl() {  // P3 relabel-write slot offsets
  Tab32u t{}; for (int r = 0; r < 32; ++r) t.v[r] = sw13(loc13(ring_map((unsigned)r)));
  return t;
}
__host__ __device__ constexpr Tab32u make_sw2() {
  Tab32u t{}; for (int r = 0; r < 32; ++r) t.v[r] = sw13((unsigned)r << 6);
  return t;
}
__host__ __device__ constexpr Tab32u make_rp3() {
  Tab32u t{}; for (int r = 0; r < 32; ++r) t.v[r] = (unsigned)r << 6; return t;
}
__host__ __device__ constexpr Tab32u make_t4() {    // P4 reg-chain offsets (bits 10..15)
  Tab32u t{};
  for (int r = 0; r < 32; ++r) {
    unsigned r0 = r & 1, r1 = (r >> 1) & 1, r2 = (r >> 2) & 1, r3 = (r >> 3) & 1, r4 = (r >> 4) & 1;
    t.v[r] = (r0 << 10) | ((r0 ^ r1) << 11) | ((r1 ^ r2) << 12) |
             ((r2 ^ r3) << 13) | ((r3 ^ r4) << 14) | (r4 << 15);
  }
  return t;
}
__device__ constexpr Tab32u RX2  = make_rx2();
__device__ constexpr Tab32u SWRL = make_swrl();
__device__ constexpr Tab32u SW2  = make_sw2();
__device__ constexpr Tab32u RP3  = make_rp3();
__device__ constexpr Tab32u T4   = make_t4();

// ---------------------------------------------------------------------------
// Gate coefficients U = RZ(phi) @ RY(theta), wave-uniform.
// ---------------------------------------------------------------------------
struct U2 { float r00, i00, r01, i01, r10, i10, r11, i11; };

__global__ void k_prep(const float* __restrict__ params, float* __restrict__ uc) {
  int g = threadIdx.x;
  if (g >= 48) return;
  float th = 0.5f * params[g * 2 + 0];
  float ph = 0.5f * params[g * 2 + 1];
  float st, ct, sp, cp;
  __sincosf(th, &st, &ct);
  __sincosf(ph, &sp, &cp);
  float* u = uc + g * 8;
  u[0] =  cp * ct; u[1] = -sp * ct;
  u[2] = -cp * st; u[3] =  sp * st;
  u[4] =  cp * st; u[5] =  sp * st;
  u[6] =  cp * ct; u[7] =  sp * ct;
}

__device__ inline U2 load_u(const float* __restrict__ uc, int d, int w) {
  const float* u = uc + (d * 16 + w) * 8;
  U2 r;
  r.r00 = u[0]; r.i00 = u[1]; r.r01 = u[2]; r.i01 = u[3];
  r.r10 = u[4]; r.i10 = u[5]; r.r11 = u[6]; r.i11 = u[7];
  return r;
}

// Packed complex pair-update: (x,y) = C0*A + C0S*(-Ay,Ax) + C1*B + C1S*(-By,Bx).
// Bitwise identical to the R4 scalar fmaf chain (component-wise same order).
__device__ inline v2f cmaddp(v2f C0, v2f C0S, v2f A, v2f C1, v2f C1S, v2f B) {
  v2f AS; AS.x = -A.y; AS.y = A.x;
  v2f BS; BS.x = -B.y; BS.y = B.x;
  return __builtin_elementwise_fma(C0, A,
         __builtin_elementwise_fma(C0S, AS,
         __builtin_elementwise_fma(C1, B, C1S * BS)));
}
__device__ inline v2f splat(float s) { v2f r; r.x = s; r.y = s; return r; }

__device__ inline v2f h_to_f2(float bits) {
  __half2 h = __builtin_bit_cast(__half2, bits);
  float2 f = __half22float2(h);
  v2f r; r.x = f.x; r.y = f.y;
  return r;
}
__device__ inline float f2_to_h(v2f v) {
  __half2 h = __float22half2_rn(make_float2(v.x, v.y));
  return __builtin_bit_cast(float, h);
}

template <int MASK>
__device__ inline float lane_xor_f(float v) {
  if constexpr (MASK == 1) {
    return __int_as_float(__builtin_amdgcn_update_dpp(
        0, __float_as_int(v), 0xB1, 0xF, 0xF, true));
  } else if constexpr (MASK == 2) {
    return __int_as_float(__builtin_amdgcn_update_dpp(
        0, __float_as_int(v), 0x4E, 0xF, 0xF, true));
  } else if constexpr (MASK == 3) {
    return __int_as_float(__builtin_amdgcn_update_dpp(
        0, __float_as_int(v), 0x1B, 0xF, 0xF, true));
  } else if constexpr (MASK < 32) {
    return __int_as_float(__builtin_amdgcn_ds_swizzle(
        __float_as_int(v), (MASK << 10) | 0x1F));
  } else {
    return __shfl_xor(v, MASK, 64);
  }
}
template <int MASK>
__device__ inline v2f lane_xor_v(v2f v) {
  v2f r; r.x = lane_xor_f<MASK>(v.x); r.y = lane_xor_f<MASK>(v.y);
  return r;
}

// ---------------- natural gates (algebra verified R1-R6) ----------------
template <int K>
__device__ inline void reg_gate(v2f (&a)[32], const U2 u) {
  const v2f C00 = splat(u.r00), S00 = splat(u.i00), C01 = splat(u.r01), S01 = splat(u.i01);
  const v2f C10 = splat(u.r10), S10 = splat(u.i10), C11 = splat(u.r11), S11 = splat(u.i11);
#pragma unroll
  for (int l = 0; l < 32; ++l) {
    if (l & (1 << K)) continue;
    const int p = l | (1 << K);
    const v2f A = a[l], B = a[p];
    a[l] = cmaddp(C00, S00, A, C01, S01, B);
    a[p] = cmaddp(C10, S10, A, C11, S11, B);
  }
}

template <int MASK>
__device__ inline void lane_gate(v2f (&a)[32], const U2 u, int lane) {
  const bool hi = (lane & MASK) != 0;
  const v2f C0 = splat(hi ? u.r11 : u.r00), S0 = splat(hi ? u.i11 : u.i00);
  const v2f C1 = splat(hi ? u.r10 : u.r01), S1 = splat(hi ? u.i10 : u.i01);
#pragma unroll
  for (int l = 0; l < 32; ++l) {
    v2f px = lane_xor_v<MASK>(a[l]);
    a[l] = cmaddp(C0, S0, a[l], C1, S1, px);
  }
}

template <int MASK>
__device__ inline void lane_gate_s(v2f (&a)[32], const U2 u, int hi) {
  const v2f C0 = splat(hi ? u.r11 : u.r00), S0 = splat(hi ? u.i11 : u.i00);
  const v2f C1 = splat(hi ? u.r10 : u.r01), S1 = splat(hi ? u.i10 : u.i01);
#pragma unroll
  for (int l = 0; l < 32; ++l) {
    v2f px = lane_xor_v<MASK>(a[l]);
    a[l] = cmaddp(C0, S0, a[l], C1, S1, px);
  }
}

// ---------------- fused (conjugated) gates (algebra verified R3-R6) ----------
template <int PM>
__device__ inline void fused_reg_gate(v2f (&a)[32], const U2 u, unsigned xK,
                                      const unsigned (&RX)[32], unsigned row) {
  const v2f C00 = splat(u.r00), S00 = splat(u.i00), C01 = splat(u.r01), S01 = splat(u.i01);
  const v2f C10 = splat(u.r10), S10 = splat(u.i10), C11 = splat(u.r11), S11 = splat(u.i11);
  constexpr int LB = PM & (-PM);
#pragma unroll
  for (int l = 0; l < 32; ++l) {
    if (l & LB) continue;
    const int p = l ^ PM;
    const bool s = (__popc((xK ^ RX[l]) & row) & 1) != 0;
    const v2f A = a[l], B = a[p];
    a[l] = cmaddp(s ? C11 : C00, s ? S11 : S00, A, s ? C10 : C01, s ? S10 : S01, B);
    a[p] = cmaddp(s ? C01 : C10, s ? S01 : S10, A, s ? C00 : C11, s ? S00 : S11, B);
  }
}

template <int LM>
__device__ inline void fused_lane_gate(v2f (&a)[32], const U2 u, unsigned xK,
                                       const unsigned (&RX)[32], unsigned row) {
  const v2f C00 = splat(u.r00), S00 = splat(u.i00), C01 = splat(u.r01), S01 = splat(u.i01);
  const v2f C10 = splat(u.r10), S10 = splat(u.i10), C11 = splat(u.r11), S11 = splat(u.i11);
#pragma unroll
  for (int l = 0; l < 32; ++l) {
    v2f px = lane_xor_v<LM>(a[l]);
    const bool s = (__popc((xK ^ RX[l]) & row) & 1) != 0;
    a[l] = cmaddp(s ? C11 : C00, s ? S11 : S00, a[l], s ? C10 : C01, s ? S10 : S01, px);
  }
}

template <int LM, int PM>
__device__ inline void fused_mixed_gate(v2f (&a)[32], const U2 u, unsigned xK,
                                        const unsigned (&RX)[32], unsigned row) {
  const v2f C00 = splat(u.r00), S00 = splat(u.i00), C01 = splat(u.r01), S01 = splat(u.i01);
  const v2f C10 = splat(u.r10), S10 = splat(u.i10), C11 = splat(u.r11), S11 = splat(u.i11);
  constexpr int LB = PM & (-PM);
#pragma unroll
  for (int l = 0; l < 32; ++l) {
    if (l & LB) continue;
    const int p = l ^ PM;
    const v2f A = a[l], B = a[p];
    v2f pa = lane_xor_v<LM>(B);
    v2f pb = lane_xor_v<LM>(A);
    const bool sl = (__popc((xK ^ RX[l]) & row) & 1) != 0;
    const bool sp = (__popc((xK ^ RX[p]) & row) & 1) != 0;
    a[l] = cmaddp(sl ? C11 : C00, sl ? S11 : S00, A, sl ? C10 : C01, sl ? S10 : S01, pa);
    a[p] = cmaddp(sp ? C11 : C00, sp ? S11 : S00, B, sp ? C10 : C01, sp ? S10 : S01, pb);
  }
}

// ---------------------------------------------------------------------------
// P1: L0 on x0..x10 (wires 15..5). fp32 float4 in, fp16 out packed 16B/lane.
// (R4 structure, verified)
// ---------------------------------------------------------------------------
__global__ __launch_bounds__(256, 4)
void k_p1(const float* __restrict__ in, __half2* __restrict__ dstb,
          const float* __restrict__ uc) {
  const int b = blockIdx.x >> 3;
  const unsigned hi = blockIdx.x & 7;
  const unsigned wg = threadIdx.x >> 6;
  const unsigned lane = threadIdx.x & 63;
  const unsigned xK = (hi << 13) | (wg << 11) | (lane << 2);
  const float* src = in + (size_t)b * DIMQ;
  v2f a[32];
#pragma unroll
  for (int c = 0; c < 8; ++c) {
    float4 q = *(const float4*)(src + xK + ((unsigned)c << 8));
    a[c * 4 + 0].x = q.x; a[c * 4 + 0].y = 0.f;
    a[c * 4 + 1].x = q.y; a[c * 4 + 1].y = 0.f;
    a[c * 4 + 2].x = q.z; a[c * 4 + 2].y = 0.f;
    a[c * 4 + 3].x = q.w; a[c * 4 + 3].y = 0.f;
  }
  reg_gate<0>(a, load_u(uc, 0, 15));
  reg_gate<1>(a, load_u(uc, 0, 14));
  lane_gate<1 >(a, load_u(uc, 0, 13), lane);
  lane_gate<2 >(a, load_u(uc, 0, 12), lane);
  lane_gate<4 >(a, load_u(uc, 0, 11), lane);
  lane_gate<8 >(a, load_u(uc, 0, 10), lane);
  lane_gate<16>(a, load_u(uc, 0, 9 ), lane);
  lane_gate<32>(a, load_u(uc, 0, 8 ), lane);
  reg_gate<2>(a, load_u(uc, 0, 7));
  reg_gate<3>(a, load_u(uc, 0, 6));
  reg_gate<4>(a, load_u(uc, 0, 5));
  float* dst = (float*)(dstb + (size_t)b * DIMQ);
#pragma unroll
  for (int c = 0; c < 8; ++c) {
    float4 q;
    q.x = f2_to_h(a[c * 4 + 0]);
    q.y = f2_to_h(a[c * 4 + 1]);
    q.z = f2_to_h(a[c * 4 + 2]);
    q.w = f2_to_h(a[c * 4 + 3]);
    *(float4*)(dst + xK + ((unsigned)c << 8)) = q;
  }
}

// ---------------------------------------------------------------------------
// P2: L0 x11..x15 (wires 4..0) + fused L1 b in {0..5,12..15}. NATURAL store.
// (R4 structure, verified)
// ---------------------------------------------------------------------------
__global__ __launch_bounds__(256, 4)
void k_p2(const __half2* __restrict__ srcb, __half2* __restrict__ dstb,
          const float* __restrict__ uc) {
  const int b = blockIdx.x >> 3;
  const unsigned t8 = blockIdx.x & 7;
  const unsigned wg = threadIdx.x >> 6;
  const unsigned lane = threadIdx.x & 63;
  const unsigned xK = (t8 << 8) | (wg << 6) | lane;
  const float* src = (const float*)(srcb + (size_t)b * DIMQ);
  float* dst = (float*)(dstb + (size_t)b * DIMQ);
  v2f a[32];
#pragma unroll
  for (int r = 0; r < 32; ++r)
    a[r] = h_to_f2(src[((unsigned)r << 11) | xK]);
  reg_gate<0>(a, load_u(uc, 0, 4));
  reg_gate<1>(a, load_u(uc, 0, 3));
  reg_gate<2>(a, load_u(uc, 0, 2));
  reg_gate<3>(a, load_u(uc, 0, 1));
  reg_gate<4>(a, load_u(uc, 0, 0));
  fused_lane_gate<3 >(a, load_u(uc, 1, 14), xK, RX2.v, row_of(1));
  fused_lane_gate<6 >(a, load_u(uc, 1, 13), xK, RX2.v, row_of(2));
  fused_lane_gate<12>(a, load_u(uc, 1, 12), xK, RX2.v, row_of(3));
  fused_lane_gate<24>(a, load_u(uc, 1, 11), xK, RX2.v, row_of(4));
  fused_lane_gate<48>(a, load_u(uc, 1, 10), xK, RX2.v, row_of(5));
  fused_mixed_gate<1, 0x18>(a, load_u(uc, 1, 15), xK, RX2.v, 0xFFFFu);
  fused_reg_gate<3 >(a, load_u(uc, 1, 3), xK, RX2.v, row_of(12));
  fused_reg_gate<6 >(a, load_u(uc, 1, 2), xK, RX2.v, row_of(13));
  fused_reg_gate<12>(a, load_u(uc, 1, 1), xK, RX2.v, row_of(14));
  fused_reg_gate<24>(a, load_u(uc, 1, 0), xK, RX2.v, row_of(15));
#pragma unroll
  for (int r = 0; r < 32; ++r)
    dst[((unsigned)r << 11) | xK] = f2_to_h(a[r]);
}

// ---------------------------------------------------------------------------
// P3: LDS-routed ring relabel (R4 structure, verified).
// ---------------------------------------------------------------------------
__global__ __launch_bounds__(256, 3)
void k_p3(const __half2* __restrict__ srcb, __half2* __restrict__ dstb,
          const float* __restrict__ uc) {
  __shared__ float lds[8192];
  const int b = blockIdx.x >> 3;
  const unsigned tb = blockIdx.x & 7;
  const unsigned x12 = tb & 1u, x13 = (tb >> 1) & 1u, tt = tb >> 2;
  const unsigned tid = threadIdx.x;
  const float* src = (const float*)(srcb + (size_t)b * DIMQ);
  float* dst = (float*)(dstb + (size_t)b * DIMQ);
#pragma unroll
  for (unsigned c = 0; c < 2; ++c) {
    const unsigned gbase = (c << 14) | ((c ^ tt) << 15) | (x13 << 13) | (x12 << 12);
#pragma unroll
    for (unsigned j = 0; j < 4; ++j) {
      const unsigned e = j * 1024u + tid * 4u;
      float4 q = *(const float4*)(src + gbase + e);
      const unsigned idx = (c << 12) | e;
      const unsigned m = (idx >> 5) & 31u;
      if (m & 1u) { float s0 = q.x; q.x = q.y; q.y = s0; s0 = q.z; q.z = q.w; q.w = s0; }
      if (m & 2u) { float s0 = q.x, s1 = q.y; q.x = q.z; q.y = q.w; q.z = s0; q.w = s1; }
      *(float4*)&lds[(idx ^ m) & ~3u] = q;
    }
  }
  __syncthreads();
  const unsigned lane = tid & 63u, wv = tid >> 6;
  const unsigned w0 = wv & 1u, w1 = wv >> 1;
  const unsigned g = (lane ^ (lane >> 1)) & 63u;
  const unsigned x5 = (lane ^ w0) & 1u;
  const unsigned xloc  = (x5 << 5) | (g << 6) | (w1 << 12);
  const unsigned xfull = (x5 << 5) | (g << 6) | (x12 << 12) | (x13 << 13)
                       | (w1 << 14) | ((w1 ^ tt) << 15);
  const unsigned sb1 = sw13(xloc);
  v2f a[32];
#pragma unroll
  for (unsigned r = 0; r < 32; ++r) a[r] = h_to_f2(lds[sb1 ^ r]);
  lane_gate_s<1 >(a, load_u(uc, 1, 9), __popc(xfull & row_of(6 )) & 1);
  lane_gate_s<2 >(a, load_u(uc, 1, 8), __popc(xfull & row_of(7 )) & 1);
  lane_gate_s<4 >(a, load_u(uc, 1, 7), __popc(xfull & row_of(8 )) & 1);
  lane_gate_s<8 >(a, load_u(uc, 1, 6), __popc(xfull & row_of(9 )) & 1);
  lane_gate_s<16>(a, load_u(uc, 1, 5), __popc(xfull & row_of(10)) & 1);
  lane_gate_s<32>(a, load_u(uc, 1, 4), __popc(xfull & row_of(11)) & 1);
  const unsigned swzr = sw13(loc13(ring_map(xfull)));
  __syncthreads();
#pragma unroll
  for (unsigned r = 0; r < 32; ++r) lds[swzr ^ SWRL.v[r]] = f2_to_h(a[r]);
  __syncthreads();
  const unsigned z12 = x12 ^ x13 ^ tt, z13 = x13 ^ tt, z14 = tt;
  const unsigned zloc2 = lane | (w0 << 11) | (w1 << 12);
  const unsigned sb2 = sw13(zloc2);
  const unsigned z16b = lane | (w0 << 11) | (z12 << 12) | (z13 << 13)
                      | (z14 << 14) | (w1 << 15);
#pragma unroll
  for (unsigned r = 0; r < 32; ++r) a[r] = h_to_f2(lds[sb2 ^ SW2.v[r]]);
  fused_lane_gate<3 >(a, load_u(uc, 2, 14), z16b, RP3.v, row_of(1));
  fused_lane_gate<6 >(a, load_u(uc, 2, 13), z16b, RP3.v, row_of(2));
  fused_lane_gate<12>(a, load_u(uc, 2, 12), z16b, RP3.v, row_of(3));
  fused_lane_gate<24>(a, load_u(uc, 2, 11), z16b, RP3.v, row_of(4));
  fused_lane_gate<48>(a, load_u(uc, 2, 10), z16b, RP3.v, row_of(5));
  fused_mixed_gate<32, 1>(a, load_u(uc, 2, 9), z16b, RP3.v, row_of(6));
  fused_reg_gate<3 >(a, load_u(uc, 2, 8), z16b, RP3.v, row_of(7));
  fused_reg_gate<6 >(a, load_u(uc, 2, 7), z16b, RP3.v, row_of(8));
  fused_reg_gate<12>(a, load_u(uc, 2, 6), z16b, RP3.v, row_of(9));
  fused_reg_gate<24>(a, load_u(uc, 2, 5), z16b, RP3.v, row_of(10));
#pragma unroll
  for (unsigned r = 0; r < 32; ++r)
    dst[z16b ^ (r << 6)] = f2_to_h(a[r]);
}

// ---------------------------------------------------------------------------
// P4: L2 wires 4..0 + wire 15, fused epilogue (R4 structure, verified).
// ---------------------------------------------------------------------------
__global__ __launch_bounds__(256, 4)
void k_p4(const __half2* __restrict__ srcb, float* __restrict__ partials,
          const float* __restrict__ uc) {
  const int b = blockIdx.x >> 3;
  const unsigned q = blockIdx.x & 7;
  const unsigned wg = threadIdx.x >> 6, lane = threadIdx.x & 63u;
  const unsigned zb = lane | ((wg & 1u) << 6) | ((wg >> 1) << 7) | ((q & 1u) << 8)
                    | (((q >> 1) & 1u) << 9) | ((q >> 2) << 10);
  const float* src = (const float*)(srcb + (size_t)b * DIMQ);
  v2f a[32];
#pragma unroll
  for (unsigned r = 0; r < 32; ++r) a[r] = h_to_f2(src[zb ^ T4.v[r]]);
  fused_reg_gate<1 >(a, load_u(uc, 2, 4), zb, T4.v, row_of(11));
  fused_reg_gate<2 >(a, load_u(uc, 2, 3), zb, T4.v, row_of(12));
  fused_reg_gate<4 >(a, load_u(uc, 2, 2), zb, T4.v, row_of(13));
  fused_reg_gate<8 >(a, load_u(uc, 2, 1), zb, T4.v, row_of(14));
  fused_reg_gate<16>(a, load_u(uc, 2, 0), zb, T4.v, row_of(15));
  fused_mixed_gate<1, 16>(a, load_u(uc, 2, 15), zb, T4.v, 0xFFFFu);
  const unsigned ybase = ring_map(zb);
  float acc[16];
#pragma unroll
  for (int w = 0; w < 16; ++w) acc[w] = 0.f;
#pragma unroll
  for (unsigned r = 0; r < 32; ++r) {
    const float p = fmaf(a[r].x, a[r].x, a[r].y * a[r].y);
    const unsigned y = ybase ^ (r << 11);
#pragma unroll
    for (int w = 0; w < 16; ++w)
      acc[w] += ((y >> (15 - w)) & 1u) ? -p : p;
  }
#pragma unroll
  for (int w = 0; w < 16; ++w) {
    float s = acc[w];
    s += __shfl_xor(s, 1, 64);
    s += __shfl_xor(s, 2, 64);
    s += __shfl_xor(s, 4, 64);
    s += __shfl_xor(s, 8, 64);
    s += __shfl_xor(s, 16, 64);
    s += __shfl_xor(s, 32, 64);
    acc[w] = s;
  }
  if (lane == 0) {
    const unsigned t = q * 4 + wg;
    float* dstp = partials + ((size_t)b * 32 + t) * 16;
#pragma unroll
    for (int w = 0; w < 16; ++w) dstp[w] = acc[w];
  }
}

__global__ __launch_bounds__(256)
void k_head(const float* __restrict__ partials, const float* __restrict__ hw,
            const float* __restrict__ hb, float* __restrict__ out) {
  const int b = blockIdx.x;
  const int t = threadIdx.x;
  const int w = t & 15;
  const int i = t >> 4;
  float s = partials[((size_t)b * 32 + i) * 16 + w] +
            partials[((size_t)b * 32 + i + 16) * 16 + w];
  __shared__ float red[256];
  __shared__ float feats[16];
  red[t] = s;
  __syncthreads();
  if (t < 16) {
    float f = 0.f;
    for (int j = 0; j < 16; ++j) f += red[j * 16 + t];
    feats[t] = f;
  }
  __syncthreads();
  if (t == 0) {
    float o = hb[0];
    for (int w2 = 0; w2 < 16; ++w2) o = fmaf(feats[w2], hw[w2], o);
    out[b] = o;
  }
}

extern "C" void kernel_launch(void* const* d_in, const int* in_sizes, int n_in,
                              void* d_out, int out_size, void* d_ws, size_t ws_size,
                              hipStream_t stream) {
  const float* state  = (const float*)d_in[0];   // (128, 65536) f32
  const float* params = (const float*)d_in[1];   // (3, 16, 2)   f32
  const float* head_w = (const float*)d_in[2];   // (1, 16)      f32
  const float* head_b = (const float*)d_in[3];   // (1,)         f32
  float* out = (float*)d_out;                    // (128,)       f32

  __half2* bufA = (__half2*)d_ws;
  __half2* bufB = bufA + (size_t)DIMQ * BQ;
  __half2* bufC = bufB + (size_t)DIMQ * BQ;
  float*   partials = (float*)(bufC + (size_t)DIMQ * BQ);
  float*   uc = partials + (size_t)BQ * 32 * 16;

  k_prep<<<dim3(1), dim3(64), 0, stream>>>(params, uc);

  const dim3 g(1024), blk(256);
  k_p1<<<g, blk, 0, stream>>>(state, bufA, uc);
  k_p2<<<g, blk, 0, stream>>>(bufA, bufB, uc);
  k_p3<<<g, blk, 0, stream>>>(bufB, bufC, uc);
  k_p4<<<g, blk, 0, stream>>>(bufC, partials, uc);
  k_head<<<dim3(128), blk, 0, stream>>>(partials, head_w, head_b, out);
}